// Round 8
// baseline (3798.953 us; speedup 1.0000x reference)
//
#include <hip/hip_runtime.h>
#include <hip/hip_bf16.h>

typedef __hip_bfloat16 bf16;
typedef __attribute__((ext_vector_type(8))) short short8;
typedef __attribute__((ext_vector_type(4))) short short4v;
typedef __attribute__((ext_vector_type(4))) float f32x4;

#define NBLK 192
#define HALF_BLKS 96
#define SMEM_BYTES 147456
#define W0_STRIDE 1152   // 9*128 -> XOR swizzle row-closed

__device__ __forceinline__ float sigm(float x) { return 1.0f / (1.0f + __expf(-x)); }

__device__ __forceinline__ short f2bf(float f) {
    union { float f; unsigned int u; } v; v.f = f;
    unsigned int r = v.u + 0x7fffu + ((v.u >> 16) & 1u);
    return (short)(r >> 16);
}

// ---- coherence-point (L1+L2 bypass) ops ----
__device__ __forceinline__ void store_short_wt(bf16* p, short v) {
    asm volatile("global_store_short %0, %1, off sc0 sc1"
                 :: "v"(p), "v"((int)(unsigned short)v) : "memory");
}
__device__ __forceinline__ void store_dword_wt(float* p, float v) {
    asm volatile("global_store_dword %0, %1, off sc0 sc1"
                 :: "v"(p), "v"(v) : "memory");
}
__device__ __forceinline__ unsigned poll_dword_wt(const unsigned* p) {   // waits inside
    unsigned v;
    asm volatile("global_load_dword %0, %1, off sc0 sc1\n\ts_waitcnt vmcnt(0)"
                 : "=v"(v) : "v"(p) : "memory");
    return v;
}
__device__ __forceinline__ short8 load_b16x8_wt(const bf16* p) {         // NO wait inside
    short8 v;
    asm volatile("global_load_dwordx4 %0, %1, off sc0 sc1"
                 : "=v"(v) : "v"(p) : "memory");
    return v;
}
__device__ __forceinline__ float load_f32_wt(const float* p) {           // NO wait inside
    float v;
    asm volatile("global_load_dword %0, %1, off sc0 sc1"
                 : "=v"(v) : "v"(p) : "memory");
    return v;
}
__device__ __forceinline__ void vmcnt0() {
    asm volatile("s_waitcnt vmcnt(0)" ::: "memory");
}
__device__ __forceinline__ void ldrain() {   // order VALU consumers after the wait (rule #18)
    vmcnt0();
    __builtin_amdgcn_sched_barrier(0);
}

// ---------------- workspace layout ----------------
#define WS_H0      0x000000
#define WS_H1      0x080000
#define WS_PART    0x100000
#define WS_CNT     0x140000   // 2 half-counters, 128B apart
#define WS_XBF     0x150000
#define WS_W       0x200000
#define WS_EWIH0   0xE00000
#define WS_DWIH0   0xE08000
#define WS_ZERO_BYTES 0x150000

// ---------------- fp32 -> bf16 conversion ----------------
struct CvtEntry { const float* s; bf16* d; int n; };
struct CvtArgs  { CvtEntry e[9]; };

__global__ __launch_bounds__(256) void convert_kernel(CvtArgs a)
{
    CvtEntry en = a.e[blockIdx.y];
    int n4 = en.n >> 2;
    const float4* s4 = (const float4*)en.s;
    short4v* d4 = (short4v*)en.d;
    for (int i = blockIdx.x * blockDim.x + threadIdx.x; i < n4;
         i += gridDim.x * blockDim.x) {
        float4 f = s4[i];
        short4v o;
        o[0] = f2bf(f.x); o[1] = f2bf(f.y); o[2] = f2bf(f.z); o[3] = f2bf(f.w);
        d4[i] = o;
    }
}

__global__ void init_kernel(unsigned int* ws)
{
    const int total = WS_ZERO_BYTES / 4;
    for (int i = blockIdx.x * blockDim.x + threadIdx.x; i < total;
         i += gridDim.x * blockDim.x)
        ws[i] = 0u;
}

// ---------------- kernel args ----------------
struct KArgs {
    const bf16 *xbf;
    const bf16 *eWhh0, *eWih1, *eWhh1, *dWhh0, *dWih1, *dWhh1, *eWih0, *dWih0;
    const float *ebih0, *ebhh0, *ebih1, *ebhh1, *dbih0, *dbhh0, *dbih1, *dbhh1;
    const float *fcW, *fcb;
    bf16 *h0a, *h0b, *h1a, *h1b;
    float *partials;
    unsigned *cnt;
    float *outp;
};

// ---------------- per-half single-phase counter barrier ----------------
// One atomic add + direct poll; no relay block, no release flag. Monotonic
// counter: barrier g complete when cnt >= HALF_BLKS*g. All cross-block data
// was written through (sc0 sc1) and vmcnt-drained before arrival.
__device__ __forceinline__ void gbar(unsigned* cnt, unsigned target)
{
    vmcnt0();          // this wave's wt-stores are at the coherence point
    __syncthreads();   // all waves' stores drained
    if (threadIdx.x == 0) {
        __hip_atomic_fetch_add(cnt, 1u, __ATOMIC_RELAXED, __HIP_MEMORY_SCOPE_AGENT);
        while (poll_dword_wt(cnt) < target)
            __builtin_amdgcn_s_sleep(1);
    }
    __syncthreads();
}

// ---------------- LDS weight loaders (unchanged, verified) ----------------
__device__ __forceinline__ void load_w0(char* lw, const bf16* Whh, const bf16* Wih, int j0, int tid)
{
    for (int u = tid; u < 64 * 68; u += 512) {
        int row = u / 68, uc = u - row * 68;
        int n = ((row >> 4) << 9) + j0 + (row & 15);
        int colel = uc << 3;
        short8 v = {0, 0, 0, 0, 0, 0, 0, 0};
        if (colel < 512)       v = *(const short8*)(Whh + (size_t)n * 512 + colel);
        else if (colel == 512) v = *(const short8*)(Wih + (size_t)n * 8);
        int off = row * W0_STRIDE + uc * 16;
        if (uc < 64) off ^= (row & 7) << 4;
        *(short8*)(lw + off) = v;
    }
}
__device__ __forceinline__ void load_w1(char* lw, const bf16* Wih, const bf16* Whh, int j0, int tid)
{
    for (int u = tid; u < 64 * 128; u += 512) {
        int row = u >> 7, uc = u & 127;
        int n = ((row >> 4) << 9) + j0 + (row & 15);
        int colel = uc << 3;
        short8 v;
        if (colel < 512) v = *(const short8*)(Wih + (size_t)n * 512 + colel);
        else             v = *(const short8*)(Whh + (size_t)n * 512 + (colel - 512));
        *(short8*)(lw + ((row * 2048 + uc * 16) ^ ((row & 7) << 4))) = v;
    }
}

// ---------------- layer-0 step (unchanged from round 7) ----------------
template<bool DEC>
__device__ __forceinline__ void l0_step(
    const bf16* __restrict__ h0cur, bf16* __restrict__ h0nxt,
    const bf16* __restrict__ xbf, int s,
    const float* __restrict__ partials, const float* __restrict__ fcb,
    float* __restrict__ outp, int t,
    char* lw, bf16* lxs,
    float* cst, const float* bsum,
    int m0, int j0, int jb, int tid)
{
    const int w = tid >> 6;
    const int l = tid & 63, lr = l & 15, lg = l >> 4;

    if (DEC) {
        #pragma unroll
        for (int p = 0; p < 2; ++p) {
            int e = p * 512 + tid, mlo = e >> 3, f = e & 7;
            if (t == 0) {
                lxs[mlo * 8 + f] = xbf[((size_t)(m0 + mlo) * 168 + 167) * 8 + f];
            } else {
                float pv[32];
                #pragma unroll
                for (int q = 0; q < 32; ++q)
                    pv[q] = load_f32_wt(partials + q * 2048 + (m0 + mlo) * 8 + f);
                ldrain();
                float sacc = fcb[f];
                #pragma unroll
                for (int q = 0; q < 32; ++q) sacc += pv[q];
                if (jb == 0) outp[(size_t)(m0 + mlo) * 192 + (t - 1) * 8 + f] = sacc;
                ((short*)lxs)[mlo * 8 + f] = f2bf(sacc);
            }
        }
        __syncthreads();
    }

    const bf16* arow = h0cur + ((size_t)(m0 + w * 16 + lr) << 9) + lg * 8;
    short8 afr[16];
    #pragma unroll
    for (int kcg = 0; kcg < 16; ++kcg)
        afr[kcg] = load_b16x8_wt(arow + kcg * 32);
    short8 ax = {0, 0, 0, 0, 0, 0, 0, 0};
    if (lg == 0) {
        if (DEC) ax = *(const short8*)(lxs + (w * 16 + lr) * 8);
        else     ax = *(const short8*)(xbf + ((size_t)(m0 + w * 16 + lr) * 168 + s) * 8);
    }
    ldrain();

    f32x4 acc[4];
    #pragma unroll
    for (int g = 0; g < 4; ++g) acc[g] = (f32x4){0.f, 0.f, 0.f, 0.f};

    #pragma unroll
    for (int kcg = 0; kcg < 17; ++kcg) {
        #pragma unroll
        for (int g = 0; g < 4; ++g) {
            int wrow = g * 16 + lr;
            int off = wrow * W0_STRIDE + kcg * 64 + lg * 16;
            if (kcg < 16) off ^= (wrow & 7) << 4;
            short8 bfr = *(const short8*)(lw + off);
            short8 av = (kcg < 16) ? afr[kcg] : ax;
            acc[g] = __builtin_amdgcn_mfma_f32_16x16x32_bf16(av, bfr, acc[g], 0, 0, 0);
        }
    }

    #pragma unroll
    for (int r = 0; r < 4; ++r) {
        float gi = acc[0][r] + bsum[0];
        float gf = acc[1][r] + bsum[1];
        float gg = acc[2][r] + bsum[2];
        float go = acc[3][r] + bsum[3];
        float cv = sigm(gf) * cst[r] + sigm(gi) * tanhf(gg);
        float hv = sigm(go) * tanhf(cv);
        cst[r] = cv;
        store_short_wt(h0nxt + ((size_t)(m0 + w * 16 + lg * 4 + r) << 9) + j0 + lr, f2bf(hv));
    }
}

// ---------------- layer-1 step (unchanged from round 7) ----------------
template<bool DEC>
__device__ __forceinline__ void l1_step(
    const bf16* __restrict__ h0src, const bf16* __restrict__ h1prev, bf16* __restrict__ h1nxt,
    float* __restrict__ partials, const float* __restrict__ wf,
    char* lw, float* lgl,
    float* cst, const float* bsum,
    int m0, int j0, int jb, int tid)
{
    const int w = tid >> 6, mt = w & 3, kh = w >> 2;
    const int l = tid & 63, lr = l & 15, lg = l >> 4;
    const bf16* A = (kh == 0) ? h0src : h1prev;
    const int colbase = (kh == 0) ? 0 : 1024;

    const bf16* arow = A + ((size_t)(m0 + mt * 16 + lr) << 9) + lg * 8;
    short8 afr[16];
    #pragma unroll
    for (int kc = 0; kc < 16; ++kc)
        afr[kc] = load_b16x8_wt(arow + kc * 32);
    ldrain();

    f32x4 acc[4];
    #pragma unroll
    for (int g = 0; g < 4; ++g) acc[g] = (f32x4){0.f, 0.f, 0.f, 0.f};

    #pragma unroll
    for (int kc = 0; kc < 16; ++kc) {
        #pragma unroll
        for (int g = 0; g < 4; ++g) {
            int wrow = g * 16 + lr;
            short8 bfr = *(const short8*)(lw + ((wrow * 2048 + colbase + kc * 64 + lg * 16) ^ ((wrow & 7) << 4)));
            acc[g] = __builtin_amdgcn_mfma_f32_16x16x32_bf16(afr[kc], bfr, acc[g], 0, 0, 0);
        }
    }

    if (kh == 1) {
        #pragma unroll
        for (int g = 0; g < 4; ++g)
            #pragma unroll
            for (int r = 0; r < 4; ++r)
                lgl[(g * 64 + mt * 16 + lg * 4 + r) * 16 + lr] = acc[g][r];
    }
    __syncthreads();
    if (kh == 0) {
        #pragma unroll
        for (int r = 0; r < 4; ++r) {
            int mrow = mt * 16 + lg * 4 + r;
            float gi = acc[0][r] + lgl[(0 * 64 + mrow) * 16 + lr] + bsum[0];
            float gf = acc[1][r] + lgl[(1 * 64 + mrow) * 16 + lr] + bsum[1];
            float gg = acc[2][r] + lgl[(2 * 64 + mrow) * 16 + lr] + bsum[2];
            float go = acc[3][r] + lgl[(3 * 64 + mrow) * 16 + lr] + bsum[3];
            float cv = sigm(gf) * cst[r] + sigm(gi) * tanhf(gg);
            float hv = sigm(go) * tanhf(cv);
            cst[r] = cv;
            store_short_wt(h1nxt + ((size_t)(m0 + mrow) << 9) + j0 + lr, f2bf(hv));
            if (DEC) {
                #pragma unroll
                for (int f = 0; f < 8; ++f) {
                    float v = hv * wf[f];
                    v += __shfl_xor(v, 1); v += __shfl_xor(v, 2);
                    v += __shfl_xor(v, 4); v += __shfl_xor(v, 8);
                    if (lr == f)
                        store_dword_wt(partials + jb * 2048 + (m0 + mrow) * 8 + f, v);
                }
            }
        }
    }
}

// ---------------- persistent kernel ----------------
__global__ __launch_bounds__(512, 2) void net_kernel(KArgs a)
{
    extern __shared__ char smem[];
    const int tid = threadIdx.x;
    const int bid = blockIdx.x;
    const int role = (bid < 64) ? 0 : 1;
    const int sub = role == 0 ? bid : bid - 64;
    const int jb = sub & 31;
    const int mh = sub >> 5;
    const int m0 = (role == 0) ? mh * 128 : mh * 64;
    const int j0 = jb * 16;
    const int half = (role == 0) ? mh : (mh >> 1);
    unsigned* cnt = a.cnt + half * 32;   // 128B apart

    char* lw  = smem;
    float* lgl = (float*)(smem + 131072);
    bf16* lxs  = (bf16*)(smem + 64 * W0_STRIDE);

    if (role == 0) load_w0(lw, a.eWhh0, a.eWih0, j0, tid);
    else           load_w1(lw, a.eWih1, a.eWhh1, j0, tid);

    float bsum[4];
    {
        const float* bi = role == 0 ? a.ebih0 : a.ebih1;
        const float* bh = role == 0 ? a.ebhh0 : a.ebhh1;
        #pragma unroll
        for (int g2 = 0; g2 < 4; ++g2) {
            int n = (g2 << 9) + j0 + (tid & 15);
            bsum[g2] = bi[n] + bh[n];
        }
    }
    float cst[4] = {0.f, 0.f, 0.f, 0.f};
    __syncthreads();

    bf16* H0[2] = { a.h0a, a.h0b };
    bf16* H1[2] = { a.h1a, a.h1b };
    unsigned gen = 1;

    // -------- encoder --------
    for (int s = 0; s <= 168; ++s) {
        if (role == 0) {
            if (s < 168)
                l0_step<false>(H0[s & 1], H0[(s + 1) & 1], a.xbf, s,
                               nullptr, nullptr, nullptr, 0,
                               lw, lxs, cst, bsum, m0, j0, jb, tid);
        } else {
            if (s >= 1)
                l1_step<false>(H0[s & 1], H1[(s + 1) & 1], H1[s & 1],
                               nullptr, nullptr, lw, lgl, cst, bsum, m0, j0, jb, tid);
        }
        gbar(cnt, HALF_BLKS * gen); ++gen;
    }

    // -------- switch to decoder weights --------
    if (role == 0) load_w0(lw, a.dWhh0, a.dWih0, j0, tid);
    else           load_w1(lw, a.dWih1, a.dWhh1, j0, tid);
    {
        const float* bi = role == 0 ? a.dbih0 : a.dbih1;
        const float* bh = role == 0 ? a.dbhh0 : a.dbhh1;
        #pragma unroll
        for (int g2 = 0; g2 < 4; ++g2) {
            int n = (g2 << 9) + j0 + (tid & 15);
            bsum[g2] = bi[n] + bh[n];
        }
    }
    float wf[8] = {0.f, 0.f, 0.f, 0.f, 0.f, 0.f, 0.f, 0.f};
    if (role == 1) {
        #pragma unroll
        for (int f = 0; f < 8; ++f) wf[f] = a.fcW[f * 512 + j0 + (tid & 15)];
    }
    __syncthreads();

    // -------- decoder --------
    for (int t = 0; t < 24; ++t) {
        if (role == 0)
            l0_step<true>(H0[t & 1], H0[(t + 1) & 1], a.xbf, 0,
                          a.partials, a.fcb, a.outp, t,
                          lw, lxs, cst, bsum, m0, j0, jb, tid);
        gbar(cnt, HALF_BLKS * gen); ++gen;
        if (role == 1)
            l1_step<true>(H0[(t + 1) & 1], H1[t & 1], H1[(t + 1) & 1],
                          a.partials, wf, lw, lgl, cst, bsum, m0, j0, jb, tid);
        gbar(cnt, HALF_BLKS * gen); ++gen;
    }

    // -------- final pred[23] --------
    if (role == 0 && jb == 0) {
        #pragma unroll
        for (int p = 0; p < 2; ++p) {
            int e = p * 512 + tid, mlo = e >> 3, f = e & 7;
            float pv[32];
            #pragma unroll
            for (int q = 0; q < 32; ++q)
                pv[q] = load_f32_wt(a.partials + q * 2048 + (m0 + mlo) * 8 + f);
            ldrain();
            float sacc = a.fcb[f];
            #pragma unroll
            for (int q = 0; q < 32; ++q) sacc += pv[q];
            a.outp[(size_t)(m0 + mlo) * 192 + 23 * 8 + f] = sacc;
        }
    }
}

extern "C" void kernel_launch(void* const* d_in, const int* in_sizes, int n_in,
                              void* d_out, int out_size, void* d_ws, size_t ws_size,
                              hipStream_t stream)
{
    (void)in_sizes; (void)n_in; (void)out_size; (void)ws_size;
    const float* src   = (const float*)d_in[0];
    const float* eWih0 = (const float*)d_in[1];
    const float* eWhh0 = (const float*)d_in[2];
    const float* ebih0 = (const float*)d_in[3];
    const float* ebhh0 = (const float*)d_in[4];
    const float* eWih1 = (const float*)d_in[5];
    const float* eWhh1 = (const float*)d_in[6];
    const float* ebih1 = (const float*)d_in[7];
    const float* ebhh1 = (const float*)d_in[8];
    const float* dWih0 = (const float*)d_in[9];
    const float* dWhh0 = (const float*)d_in[10];
    const float* dbih0 = (const float*)d_in[11];
    const float* dbhh0 = (const float*)d_in[12];
    const float* dWih1 = (const float*)d_in[13];
    const float* dWhh1 = (const float*)d_in[14];
    const float* dbih1 = (const float*)d_in[15];
    const float* dbhh1 = (const float*)d_in[16];
    const float* fcW   = (const float*)d_in[17];
    const float* fcb   = (const float*)d_in[18];

    char* ws = (char*)d_ws;
    const int NH = 2048 * 512;

    CvtArgs ca;
    ca.e[0] = { eWhh0, (bf16*)(ws + WS_W + 0x000000), NH };
    ca.e[1] = { eWih1, (bf16*)(ws + WS_W + 0x200000), NH };
    ca.e[2] = { eWhh1, (bf16*)(ws + WS_W + 0x400000), NH };
    ca.e[3] = { dWhh0, (bf16*)(ws + WS_W + 0x600000), NH };
    ca.e[4] = { dWih1, (bf16*)(ws + WS_W + 0x800000), NH };
    ca.e[5] = { dWhh1, (bf16*)(ws + WS_W + 0xA00000), NH };
    ca.e[6] = { eWih0, (bf16*)(ws + WS_EWIH0), 2048 * 8 };
    ca.e[7] = { dWih0, (bf16*)(ws + WS_DWIH0), 2048 * 8 };
    ca.e[8] = { src,   (bf16*)(ws + WS_XBF),   256 * 168 * 8 };

    KArgs ka;
    ka.xbf   = (const bf16*)(ws + WS_XBF);
    ka.eWhh0 = (const bf16*)(ws + WS_W + 0x000000);
    ka.eWih1 = (const bf16*)(ws + WS_W + 0x200000);
    ka.eWhh1 = (const bf16*)(ws + WS_W + 0x400000);
    ka.dWhh0 = (const bf16*)(ws + WS_W + 0x600000);
    ka.dWih1 = (const bf16*)(ws + WS_W + 0x800000);
    ka.dWhh1 = (const bf16*)(ws + WS_W + 0xA00000);
    ka.eWih0 = (const bf16*)(ws + WS_EWIH0);
    ka.dWih0 = (const bf16*)(ws + WS_DWIH0);
    ka.ebih0 = ebih0; ka.ebhh0 = ebhh0; ka.ebih1 = ebih1; ka.ebhh1 = ebhh1;
    ka.dbih0 = dbih0; ka.dbhh0 = dbhh0; ka.dbih1 = dbih1; ka.dbhh1 = dbhh1;
    ka.fcW = fcW; ka.fcb = fcb;
    ka.h0a = (bf16*)(ws + WS_H0);
    ka.h0b = (bf16*)(ws + WS_H0 + 0x40000);
    ka.h1a = (bf16*)(ws + WS_H1);
    ka.h1b = (bf16*)(ws + WS_H1 + 0x40000);
    ka.partials = (float*)(ws + WS_PART);
    ka.cnt      = (unsigned*)(ws + WS_CNT);
    ka.outp     = (float*)d_out;

    hipFuncSetAttribute((const void*)net_kernel,
                        hipFuncAttributeMaxDynamicSharedMemorySize, SMEM_BYTES);

    convert_kernel<<<dim3(128, 9), dim3(256), 0, stream>>>(ca);
    init_kernel<<<dim3(512), dim3(256), 0, stream>>>((unsigned int*)ws);
    net_kernel<<<dim3(NBLK), dim3(512), SMEM_BYTES, stream>>>(ka);
}

// Round 9
// 2302.867 us; speedup vs baseline: 1.6497x; 1.6497x over previous
//
#include <hip/hip_runtime.h>
#include <hip/hip_bf16.h>

typedef __hip_bfloat16 bf16;
typedef __attribute__((ext_vector_type(8))) short short8;
typedef __attribute__((ext_vector_type(4))) short short4v;
typedef __attribute__((ext_vector_type(4))) float f32x4;

#define NBLK 192
#define SMEM_BYTES 147456
#define W0_STRIDE 1152   // 9*128 -> XOR swizzle row-closed

__device__ __forceinline__ float sigm(float x) { return 1.0f / (1.0f + __expf(-x)); }

__device__ __forceinline__ short f2bf(float f) {
    union { float f; unsigned int u; } v; v.f = f;
    unsigned int r = v.u + 0x7fffu + ((v.u >> 16) & 1u);
    return (short)(r >> 16);
}

// ---- coherence-point (L1+L2 bypass) ops ----
__device__ __forceinline__ void store_short_wt(bf16* p, short v) {
    asm volatile("global_store_short %0, %1, off sc0 sc1"
                 :: "v"(p), "v"((int)(unsigned short)v) : "memory");
}
__device__ __forceinline__ void store_dword_wt(float* p, float v) {
    asm volatile("global_store_dword %0, %1, off sc0 sc1"
                 :: "v"(p), "v"(v) : "memory");
}
__device__ __forceinline__ void store_dword_wt_u(unsigned* p, unsigned v) {
    asm volatile("global_store_dword %0, %1, off sc0 sc1"
                 :: "v"(p), "v"(v) : "memory");
}
__device__ __forceinline__ unsigned poll_dword_wt(const unsigned* p) {   // waits inside
    unsigned v;
    asm volatile("global_load_dword %0, %1, off sc0 sc1\n\ts_waitcnt vmcnt(0)"
                 : "=v"(v) : "v"(p) : "memory");
    return v;
}
__device__ __forceinline__ short8 load_b16x8_wt(const bf16* p) {         // NO wait inside
    short8 v;
    asm volatile("global_load_dwordx4 %0, %1, off sc0 sc1"
                 : "=v"(v) : "v"(p) : "memory");
    return v;
}
__device__ __forceinline__ float load_f32_wt(const float* p) {           // NO wait inside
    float v;
    asm volatile("global_load_dword %0, %1, off sc0 sc1"
                 : "=v"(v) : "v"(p) : "memory");
    return v;
}
__device__ __forceinline__ void vmcnt0() {
    asm volatile("s_waitcnt vmcnt(0)" ::: "memory");
}
__device__ __forceinline__ void ldrain() {
    vmcnt0();
    __builtin_amdgcn_sched_barrier(0);
}

// ---------------- workspace layout ----------------
#define WS_H0      0x000000   // 3 x 256x512 bf16 = 768KB (triple buffer)
#define WS_H1      0x0C0000   // 768KB
#define WS_PART    0x180000   // [32][256][8] f32 = 256KB
#define WS_CNT     0x1C0000   // 192 counters, 128B apart = 24KB
#define WS_XBF     0x1D0000   // src bf16 672KB
#define WS_W       0x280000   // 6 x 2MB bf16
#define WS_EWIH0   0xE80000
#define WS_DWIH0   0xE88000
#define WS_ZERO_BYTES 0x1D0000

// ---------------- fp32 -> bf16 conversion ----------------
struct CvtEntry { const float* s; bf16* d; int n; };
struct CvtArgs  { CvtEntry e[9]; };

__global__ __launch_bounds__(256) void convert_kernel(CvtArgs a)
{
    CvtEntry en = a.e[blockIdx.y];
    int n4 = en.n >> 2;
    const float4* s4 = (const float4*)en.s;
    short4v* d4 = (short4v*)en.d;
    for (int i = blockIdx.x * blockDim.x + threadIdx.x; i < n4;
         i += gridDim.x * blockDim.x) {
        float4 f = s4[i];
        short4v o;
        o[0] = f2bf(f.x); o[1] = f2bf(f.y); o[2] = f2bf(f.z); o[3] = f2bf(f.w);
        d4[i] = o;
    }
}

__global__ void init_kernel(unsigned int* ws)
{
    const int total = WS_ZERO_BYTES / 4;
    for (int i = blockIdx.x * blockDim.x + threadIdx.x; i < total;
         i += gridDim.x * blockDim.x)
        ws[i] = 0u;
}

// ---------------- kernel args ----------------
struct KArgs {
    const bf16 *xbf;
    const bf16 *eWhh0, *eWih1, *eWhh1, *dWhh0, *dWih1, *dWhh1, *eWih0, *dWih0;
    const float *ebih0, *ebhh0, *ebih1, *ebhh1, *dbih0, *dbhh0, *dbih1, *dbhh1;
    const float *fcW, *fcb;
    bf16 *h0base, *h1base;
    float *partials;
    unsigned *cnt;
    float *outp;
};

// ---------------- point-to-point poll: wave 0 checks group minima ----------------
// Counters are per-block "products completed", written through; polled through.
// Lanes 0..31 check 32 counters at baseA (>= tgtA); lanes 0..nB-1 check baseB.
__device__ __forceinline__ void pollw(const unsigned* baseA, unsigned tgtA,
                                      const unsigned* baseB, unsigned tgtB, int nB,
                                      int tid)
{
    if (tid < 64) {
        const unsigned* pA = (tid < 32) ? baseA + tid * 32 : nullptr;
        const unsigned* pB = (tid < nB) ? baseB + tid * 32 : nullptr;
        for (;;) {
            int ok = 1;
            if (pA) ok &= (poll_dword_wt(pA) >= tgtA) ? 1 : 0;
            if (pB) ok &= (poll_dword_wt(pB) >= tgtB) ? 1 : 0;
            if (__all(ok)) break;
            __builtin_amdgcn_s_sleep(1);
        }
    }
    __syncthreads();
}

// publish: all waves drain stores, then thread 0 writes the counter
__device__ __forceinline__ void publish(unsigned* mycnt, unsigned val, int tid)
{
    vmcnt0();
    __syncthreads();
    if (tid == 0) store_dword_wt_u(mycnt, val);
}

// ---------------- LDS weight loaders (verified) ----------------
__device__ __forceinline__ void load_w0(char* lw, const bf16* Whh, const bf16* Wih, int j0, int tid)
{
    for (int u = tid; u < 64 * 68; u += 512) {
        int row = u / 68, uc = u - row * 68;
        int n = ((row >> 4) << 9) + j0 + (row & 15);
        int colel = uc << 3;
        short8 v = {0, 0, 0, 0, 0, 0, 0, 0};
        if (colel < 512)       v = *(const short8*)(Whh + (size_t)n * 512 + colel);
        else if (colel == 512) v = *(const short8*)(Wih + (size_t)n * 8);
        int off = row * W0_STRIDE + uc * 16;
        if (uc < 64) off ^= (row & 7) << 4;
        *(short8*)(lw + off) = v;
    }
}
__device__ __forceinline__ void load_w1(char* lw, const bf16* Wih, const bf16* Whh, int j0, int tid)
{
    for (int u = tid; u < 64 * 128; u += 512) {
        int row = u >> 7, uc = u & 127;
        int n = ((row >> 4) << 9) + j0 + (row & 15);
        int colel = uc << 3;
        short8 v;
        if (colel < 512) v = *(const short8*)(Wih + (size_t)n * 512 + colel);
        else             v = *(const short8*)(Whh + (size_t)n * 512 + (colel - 512));
        *(short8*)(lw + ((row * 2048 + uc * 16) ^ ((row & 7) << 4))) = v;
    }
}

// ---------------- layer-0 step (verified round-7 compute) ----------------
template<bool DEC>
__device__ __forceinline__ void l0_step(
    const bf16* __restrict__ h0cur, bf16* __restrict__ h0nxt,
    const bf16* __restrict__ xbf, int s,
    const float* __restrict__ partials, const float* __restrict__ fcb,
    float* __restrict__ outp, int t,
    char* lw, bf16* lxs,
    float* cst, const float* bsum,
    int m0, int j0, int jb, int tid)
{
    const int w = tid >> 6;
    const int l = tid & 63, lr = l & 15, lg = l >> 4;

    if (DEC) {
        #pragma unroll
        for (int p = 0; p < 2; ++p) {
            int e = p * 512 + tid, mlo = e >> 3, f = e & 7;
            if (t == 0) {
                lxs[mlo * 8 + f] = xbf[((size_t)(m0 + mlo) * 168 + 167) * 8 + f];
            } else {
                float pv[32];
                #pragma unroll
                for (int q = 0; q < 32; ++q)
                    pv[q] = load_f32_wt(partials + q * 2048 + (m0 + mlo) * 8 + f);
                ldrain();
                float sacc = fcb[f];
                #pragma unroll
                for (int q = 0; q < 32; ++q) sacc += pv[q];
                if (jb == 0) outp[(size_t)(m0 + mlo) * 192 + (t - 1) * 8 + f] = sacc;
                ((short*)lxs)[mlo * 8 + f] = f2bf(sacc);
            }
        }
        __syncthreads();
    }

    const bf16* arow = h0cur + ((size_t)(m0 + w * 16 + lr) << 9) + lg * 8;
    short8 afr[16];
    #pragma unroll
    for (int kcg = 0; kcg < 16; ++kcg)
        afr[kcg] = load_b16x8_wt(arow + kcg * 32);
    short8 ax = {0, 0, 0, 0, 0, 0, 0, 0};
    if (lg == 0) {
        if (DEC) ax = *(const short8*)(lxs + (w * 16 + lr) * 8);
        else     ax = *(const short8*)(xbf + ((size_t)(m0 + w * 16 + lr) * 168 + s) * 8);
    }
    ldrain();

    f32x4 acc[4];
    #pragma unroll
    for (int g = 0; g < 4; ++g) acc[g] = (f32x4){0.f, 0.f, 0.f, 0.f};

    #pragma unroll
    for (int kcg = 0; kcg < 17; ++kcg) {
        #pragma unroll
        for (int g = 0; g < 4; ++g) {
            int wrow = g * 16 + lr;
            int off = wrow * W0_STRIDE + kcg * 64 + lg * 16;
            if (kcg < 16) off ^= (wrow & 7) << 4;
            short8 bfr = *(const short8*)(lw + off);
            short8 av = (kcg < 16) ? afr[kcg] : ax;
            acc[g] = __builtin_amdgcn_mfma_f32_16x16x32_bf16(av, bfr, acc[g], 0, 0, 0);
        }
    }

    #pragma unroll
    for (int r = 0; r < 4; ++r) {
        float gi = acc[0][r] + bsum[0];
        float gf = acc[1][r] + bsum[1];
        float gg = acc[2][r] + bsum[2];
        float go = acc[3][r] + bsum[3];
        float cv = sigm(gf) * cst[r] + sigm(gi) * tanhf(gg);
        float hv = sigm(go) * tanhf(cv);
        cst[r] = cv;
        store_short_wt(h0nxt + ((size_t)(m0 + w * 16 + lg * 4 + r) << 9) + j0 + lr, f2bf(hv));
    }
}

// ---------------- layer-1 step (verified round-7 compute) ----------------
template<bool DEC>
__device__ __forceinline__ void l1_step(
    const bf16* __restrict__ h0src, const bf16* __restrict__ h1prev, bf16* __restrict__ h1nxt,
    float* __restrict__ partials, const float* __restrict__ wf,
    char* lw, float* lgl,
    float* cst, const float* bsum,
    int m0, int j0, int jb, int tid)
{
    const int w = tid >> 6, mt = w & 3, kh = w >> 2;
    const int l = tid & 63, lr = l & 15, lg = l >> 4;
    const bf16* A = (kh == 0) ? h0src : h1prev;
    const int colbase = (kh == 0) ? 0 : 1024;

    const bf16* arow = A + ((size_t)(m0 + mt * 16 + lr) << 9) + lg * 8;
    short8 afr[16];
    #pragma unroll
    for (int kc = 0; kc < 16; ++kc)
        afr[kc] = load_b16x8_wt(arow + kc * 32);
    ldrain();

    f32x4 acc[4];
    #pragma unroll
    for (int g = 0; g < 4; ++g) acc[g] = (f32x4){0.f, 0.f, 0.f, 0.f};

    #pragma unroll
    for (int kc = 0; kc < 16; ++kc) {
        #pragma unroll
        for (int g = 0; g < 4; ++g) {
            int wrow = g * 16 + lr;
            short8 bfr = *(const short8*)(lw + ((wrow * 2048 + colbase + kc * 64 + lg * 16) ^ ((wrow & 7) << 4)));
            acc[g] = __builtin_amdgcn_mfma_f32_16x16x32_bf16(afr[kc], bfr, acc[g], 0, 0, 0);
        }
    }

    if (kh == 1) {
        #pragma unroll
        for (int g = 0; g < 4; ++g)
            #pragma unroll
            for (int r = 0; r < 4; ++r)
                lgl[(g * 64 + mt * 16 + lg * 4 + r) * 16 + lr] = acc[g][r];
    }
    __syncthreads();
    if (kh == 0) {
        #pragma unroll
        for (int r = 0; r < 4; ++r) {
            int mrow = mt * 16 + lg * 4 + r;
            float gi = acc[0][r] + lgl[(0 * 64 + mrow) * 16 + lr] + bsum[0];
            float gf = acc[1][r] + lgl[(1 * 64 + mrow) * 16 + lr] + bsum[1];
            float gg = acc[2][r] + lgl[(2 * 64 + mrow) * 16 + lr] + bsum[2];
            float go = acc[3][r] + lgl[(3 * 64 + mrow) * 16 + lr] + bsum[3];
            float cv = sigm(gf) * cst[r] + sigm(gi) * tanhf(gg);
            float hv = sigm(go) * tanhf(cv);
            cst[r] = cv;
            store_short_wt(h1nxt + ((size_t)(m0 + mrow) << 9) + j0 + lr, f2bf(hv));
            if (DEC) {
                #pragma unroll
                for (int f = 0; f < 8; ++f) {
                    float v = hv * wf[f];
                    v += __shfl_xor(v, 1); v += __shfl_xor(v, 2);
                    v += __shfl_xor(v, 4); v += __shfl_xor(v, 8);
                    if (lr == f)
                        store_dword_wt(partials + jb * 2048 + (m0 + mrow) * 8 + f, v);
                }
            }
        }
    }
}

// ---------------- persistent kernel: decoupled dataflow, no global barrier ----------------
// Product index p = 0..191 unifies encoder (0..167) and decoder (168..191).
// h buffers are mod-3 by product index; per-block progress counters give
// producer/consumer sync with 2 products of pipeline slack (WAR distance 3).
__global__ __launch_bounds__(512, 2) void net_kernel(KArgs a)
{
    extern __shared__ char smem[];
    const int tid = threadIdx.x;
    const int bid = blockIdx.x;
    const int role = (bid < 64) ? 0 : 1;
    const int sub = role == 0 ? bid : bid - 64;
    const int jb = sub & 31;
    const int grp = sub >> 5;                 // role0: mh 0..1 ; role1: mq 0..3
    const int m0 = (role == 0) ? grp * 128 : grp * 64;
    const int j0 = jb * 16;
    const int mh = (role == 0) ? grp : (grp >> 1);

    unsigned* cnt = a.cnt;
    unsigned* mycnt = cnt + ((role == 0) ? (grp * 32 + jb) : (64 + grp * 32 + jb)) * 32;
    const unsigned* l0grp = cnt + (mh * 32) * 32;            // 32 counters
    const unsigned* l1cat = cnt + (64 + 2 * mh * 32) * 32;   // 64 counters (both quarters of half)
    const unsigned* l1grp = cnt + (64 + grp * 32) * 32;      // role1 own group

    char* lw  = smem;
    float* lgl = (float*)(smem + 131072);
    bf16* lxs  = (bf16*)(smem + 64 * W0_STRIDE);

    bf16* B0[3] = { a.h0base, a.h0base + 131072, a.h0base + 262144 };
    bf16* B1[3] = { a.h1base, a.h1base + 131072, a.h1base + 262144 };

    if (role == 0) load_w0(lw, a.eWhh0, a.eWih0, j0, tid);
    else           load_w1(lw, a.eWih1, a.eWhh1, j0, tid);

    float bsum[4];
    {
        const float* bi = role == 0 ? a.ebih0 : a.ebih1;
        const float* bh = role == 0 ? a.ebhh0 : a.ebhh1;
        #pragma unroll
        for (int g2 = 0; g2 < 4; ++g2) {
            int n = (g2 << 9) + j0 + (tid & 15);
            bsum[g2] = bi[n] + bh[n];
        }
    }
    float cst[4] = {0.f, 0.f, 0.f, 0.f};
    float wf[8] = {0.f, 0.f, 0.f, 0.f, 0.f, 0.f, 0.f, 0.f};
    __syncthreads();

    if (role == 0) {
        for (int p = 0; p < 192; ++p) {
            const bool dec = p >= 168;
            if (p == 168) {
                load_w0(lw, a.dWhh0, a.dWih0, j0, tid);
                #pragma unroll
                for (int g2 = 0; g2 < 4; ++g2) {
                    int n = (g2 << 9) + j0 + (tid & 15);
                    bsum[g2] = a.dbih0[n] + a.dbhh0[n];
                }
                __syncthreads();
            }
            // need: h0_{p-1} (own-layer group >= p); WAR: L1 readers of h0_{p-3}
            // done (>= p-2); dec p>=169 additionally needs partials (L1 >= p).
            unsigned t1 = (unsigned)p;
            unsigned t2 = (p >= 169) ? (unsigned)p : (p >= 2 ? (unsigned)(p - 2) : 0u);
            pollw(l0grp, t1, l1cat, t2, 64, tid);

            if (!dec)
                l0_step<false>(B0[(p + 2) % 3], B0[p % 3], a.xbf, p,
                               nullptr, nullptr, nullptr, 0,
                               lw, lxs, cst, bsum, m0, j0, jb, tid);
            else
                l0_step<true>(B0[(p + 2) % 3], B0[p % 3], a.xbf, 0,
                              a.partials, a.fcb, a.outp, p - 168,
                              lw, lxs, cst, bsum, m0, j0, jb, tid);
            publish(mycnt, (unsigned)(p + 1), tid);
        }
        // final pred[23] from L1 product 191
        if (jb == 0) {
            pollw(l1cat, 192u, l1cat, 192u, 64, tid);
            #pragma unroll
            for (int p2 = 0; p2 < 2; ++p2) {
                int e = p2 * 512 + tid, mlo = e >> 3, f = e & 7;
                float pv[32];
                #pragma unroll
                for (int q = 0; q < 32; ++q)
                    pv[q] = load_f32_wt(a.partials + q * 2048 + (m0 + mlo) * 8 + f);
                ldrain();
                float sacc = a.fcb[f];
                #pragma unroll
                for (int q = 0; q < 32; ++q) sacc += pv[q];
                a.outp[(size_t)(m0 + mlo) * 192 + 23 * 8 + f] = sacc;
            }
        }
    } else {
        for (int q = 0; q < 192; ++q) {
            const bool dec = q >= 168;
            if (q == 168) {
                load_w1(lw, a.dWih1, a.dWhh1, j0, tid);
                #pragma unroll
                for (int g2 = 0; g2 < 4; ++g2) {
                    int n = (g2 << 9) + j0 + (tid & 15);
                    bsum[g2] = a.dbih1[n] + a.dbhh1[n];
                }
                #pragma unroll
                for (int f = 0; f < 8; ++f) wf[f] = a.fcW[f * 512 + j0 + (tid & 15)];
                __syncthreads();
            }
            // need: h0_q (L0 group >= q+1); h1_{q-1} (own group >= q).
            pollw(l0grp, (unsigned)(q + 1), l1grp, (unsigned)q, 32, tid);

            if (!dec)
                l1_step<false>(B0[q % 3], B1[(q + 2) % 3], B1[q % 3],
                               nullptr, nullptr, lw, lgl, cst, bsum, m0, j0, jb, tid);
            else
                l1_step<true>(B0[q % 3], B1[(q + 2) % 3], B1[q % 3],
                              a.partials, wf, lw, lgl, cst, bsum, m0, j0, jb, tid);
            publish(mycnt, (unsigned)(q + 1), tid);
        }
    }
}

extern "C" void kernel_launch(void* const* d_in, const int* in_sizes, int n_in,
                              void* d_out, int out_size, void* d_ws, size_t ws_size,
                              hipStream_t stream)
{
    (void)in_sizes; (void)n_in; (void)out_size; (void)ws_size;
    const float* src   = (const float*)d_in[0];
    const float* eWih0 = (const float*)d_in[1];
    const float* eWhh0 = (const float*)d_in[2];
    const float* ebih0 = (const float*)d_in[3];
    const float* ebhh0 = (const float*)d_in[4];
    const float* eWih1 = (const float*)d_in[5];
    const float* eWhh1 = (const float*)d_in[6];
    const float* ebih1 = (const float*)d_in[7];
    const float* ebhh1 = (const float*)d_in[8];
    const float* dWih0 = (const float*)d_in[9];
    const float* dWhh0 = (const float*)d_in[10];
    const float* dbih0 = (const float*)d_in[11];
    const float* dbhh0 = (const float*)d_in[12];
    const float* dWih1 = (const float*)d_in[13];
    const float* dWhh1 = (const float*)d_in[14];
    const float* dbih1 = (const float*)d_in[15];
    const float* dbhh1 = (const float*)d_in[16];
    const float* fcW   = (const float*)d_in[17];
    const float* fcb   = (const float*)d_in[18];

    char* ws = (char*)d_ws;
    const int NH = 2048 * 512;

    CvtArgs ca;
    ca.e[0] = { eWhh0, (bf16*)(ws + WS_W + 0x000000), NH };
    ca.e[1] = { eWih1, (bf16*)(ws + WS_W + 0x200000), NH };
    ca.e[2] = { eWhh1, (bf16*)(ws + WS_W + 0x400000), NH };
    ca.e[3] = { dWhh0, (bf16*)(ws + WS_W + 0x600000), NH };
    ca.e[4] = { dWih1, (bf16*)(ws + WS_W + 0x800000), NH };
    ca.e[5] = { dWhh1, (bf16*)(ws + WS_W + 0xA00000), NH };
    ca.e[6] = { eWih0, (bf16*)(ws + WS_EWIH0), 2048 * 8 };
    ca.e[7] = { dWih0, (bf16*)(ws + WS_DWIH0), 2048 * 8 };
    ca.e[8] = { src,   (bf16*)(ws + WS_XBF),   256 * 168 * 8 };

    KArgs ka;
    ka.xbf   = (const bf16*)(ws + WS_XBF);
    ka.eWhh0 = (const bf16*)(ws + WS_W + 0x000000);
    ka.eWih1 = (const bf16*)(ws + WS_W + 0x200000);
    ka.eWhh1 = (const bf16*)(ws + WS_W + 0x400000);
    ka.dWhh0 = (const bf16*)(ws + WS_W + 0x600000);
    ka.dWih1 = (const bf16*)(ws + WS_W + 0x800000);
    ka.dWhh1 = (const bf16*)(ws + WS_W + 0xA00000);
    ka.eWih0 = (const bf16*)(ws + WS_EWIH0);
    ka.dWih0 = (const bf16*)(ws + WS_DWIH0);
    ka.ebih0 = ebih0; ka.ebhh0 = ebhh0; ka.ebih1 = ebih1; ka.ebhh1 = ebhh1;
    ka.dbih0 = dbih0; ka.dbhh0 = dbhh0; ka.dbih1 = dbih1; ka.dbhh1 = dbhh1;
    ka.fcW = fcW; ka.fcb = fcb;
    ka.h0base = (bf16*)(ws + WS_H0);
    ka.h1base = (bf16*)(ws + WS_H1);
    ka.partials = (float*)(ws + WS_PART);
    ka.cnt      = (unsigned*)(ws + WS_CNT);
    ka.outp     = (float*)d_out;

    hipFuncSetAttribute((const void*)net_kernel,
                        hipFuncAttributeMaxDynamicSharedMemorySize, SMEM_BYTES);

    convert_kernel<<<dim3(128, 9), dim3(256), 0, stream>>>(ca);
    init_kernel<<<dim3(512), dim3(256), 0, stream>>>((unsigned int*)ws);
    net_kernel<<<dim3(NBLK), dim3(512), SMEM_BYTES, stream>>>(ka);
}

// Round 10
// 2302.507 us; speedup vs baseline: 1.6499x; 1.0002x over previous
//
#include <hip/hip_runtime.h>
#include <hip/hip_bf16.h>

typedef __hip_bfloat16 bf16;
typedef __attribute__((ext_vector_type(8))) short short8;
typedef __attribute__((ext_vector_type(4))) short short4v;
typedef __attribute__((ext_vector_type(4))) float f32x4;

#define NBLK 192
#define SMEM_BYTES 147456
#define W0_STRIDE 1152   // 9*128 -> XOR swizzle row-closed

__device__ __forceinline__ float sigm(float x) { return 1.0f / (1.0f + __expf(-x)); }

__device__ __forceinline__ short f2bf(float f) {
    union { float f; unsigned int u; } v; v.f = f;
    unsigned int r = v.u + 0x7fffu + ((v.u >> 16) & 1u);
    return (short)(r >> 16);
}

// ---- coherence-point (L1+L2 bypass) ops ----
__device__ __forceinline__ void store_short_wt(bf16* p, short v) {
    asm volatile("global_store_short %0, %1, off sc0 sc1"
                 :: "v"(p), "v"((int)(unsigned short)v) : "memory");
}
__device__ __forceinline__ void store_dword_wt(float* p, float v) {
    asm volatile("global_store_dword %0, %1, off sc0 sc1"
                 :: "v"(p), "v"(v) : "memory");
}
__device__ __forceinline__ void store_dword_wt_u(unsigned* p, unsigned v) {
    asm volatile("global_store_dword %0, %1, off sc0 sc1"
                 :: "v"(p), "v"(v) : "memory");
}
__device__ __forceinline__ unsigned poll_dword_wt(const unsigned* p) {   // waits inside
    unsigned v;
    asm volatile("global_load_dword %0, %1, off sc0 sc1\n\ts_waitcnt vmcnt(0)"
                 : "=v"(v) : "v"(p) : "memory");
    return v;
}
__device__ __forceinline__ short8 load_b16x8_wt(const bf16* p) {         // NO wait inside
    short8 v;
    asm volatile("global_load_dwordx4 %0, %1, off sc0 sc1"
                 : "=v"(v) : "v"(p) : "memory");
    return v;
}
__device__ __forceinline__ float load_f32_wt(const float* p) {           // NO wait inside
    float v;
    asm volatile("global_load_dword %0, %1, off sc0 sc1"
                 : "=v"(v) : "v"(p) : "memory");
    return v;
}
__device__ __forceinline__ void vmcnt0() {
    asm volatile("s_waitcnt vmcnt(0)" ::: "memory");
}
__device__ __forceinline__ void ldrain() {
    vmcnt0();
    __builtin_amdgcn_sched_barrier(0);
}

// ---------------- workspace layout (same as round 9) ----------------
#define WS_H0      0x000000   // 3 x 256x512 bf16 = 768KB (triple buffer)
#define WS_H1      0x0C0000   // 768KB
#define WS_PART    0x180000   // 256KB
#define WS_CNT     0x1C0000   // 192 counters, 128B apart
#define WS_XBF     0x1D0000   // 672KB
#define WS_W       0x280000   // 6 x 2MB
#define WS_EWIH0   0xE80000
#define WS_DWIH0   0xE88000
#define WS_ZERO_BYTES 0x1D0000

// ---------------- fp32 -> bf16 conversion ----------------
struct CvtEntry { const float* s; bf16* d; int n; };
struct CvtArgs  { CvtEntry e[9]; };

__global__ __launch_bounds__(256) void convert_kernel(CvtArgs a)
{
    CvtEntry en = a.e[blockIdx.y];
    int n4 = en.n >> 2;
    const float4* s4 = (const float4*)en.s;
    short4v* d4 = (short4v*)en.d;
    for (int i = blockIdx.x * blockDim.x + threadIdx.x; i < n4;
         i += gridDim.x * blockDim.x) {
        float4 f = s4[i];
        short4v o;
        o[0] = f2bf(f.x); o[1] = f2bf(f.y); o[2] = f2bf(f.z); o[3] = f2bf(f.w);
        d4[i] = o;
    }
}

__global__ void init_kernel(unsigned int* ws)
{
    const int total = WS_ZERO_BYTES / 4;
    for (int i = blockIdx.x * blockDim.x + threadIdx.x; i < total;
         i += gridDim.x * blockDim.x)
        ws[i] = 0u;
}

// ---------------- kernel args ----------------
struct KArgs {
    const bf16 *xbf;
    const bf16 *eWhh0, *eWih1, *eWhh1, *dWhh0, *dWih1, *dWhh1, *eWih0, *dWih0;
    const float *ebih0, *ebhh0, *ebih1, *ebhh1, *dbih0, *dbhh0, *dbih1, *dbhh1;
    const float *fcW, *fcb;
    bf16 *h0base, *h1base;
    float *partials;
    unsigned *cnt;
    float *outp;
};

// ---------------- masked point-to-point poll ----------------
// Per-lane done flags: satisfied lanes stop issuing loads, so iterations
// shrink to the laggards and hot counter lines stop being hammered.
__device__ __forceinline__ void pollw(const unsigned* baseA, unsigned tgtA, int nA,
                                      const unsigned* baseB, unsigned tgtB, int nB,
                                      int tid)
{
    if (tid < 64) {
        const unsigned* pA = (tid < nA) ? baseA + tid * 32 : nullptr;
        const unsigned* pB = (tid < nB) ? baseB + tid * 32 : nullptr;
        bool dA = (pA == nullptr), dB = (pB == nullptr);
        for (;;) {
            if (!dA && poll_dword_wt(pA) >= tgtA) dA = true;
            if (!dB && poll_dword_wt(pB) >= tgtB) dB = true;
            if (__all(dA && dB)) break;
            __builtin_amdgcn_s_sleep(1);
        }
    }
    __syncthreads();
}

__device__ __forceinline__ void publish(unsigned* mycnt, unsigned val, int tid)
{
    vmcnt0();
    __syncthreads();
    if (tid == 0) store_dword_wt_u(mycnt, val);
}

// ---------------- LDS weight loaders (256-thread stride) ----------------
__device__ __forceinline__ void load_w0(char* lw, const bf16* Whh, const bf16* Wih, int j0, int tid)
{
    for (int u = tid; u < 64 * 68; u += 256) {
        int row = u / 68, uc = u - row * 68;
        int n = ((row >> 4) << 9) + j0 + (row & 15);
        int colel = uc << 3;
        short8 v = {0, 0, 0, 0, 0, 0, 0, 0};
        if (colel < 512)       v = *(const short8*)(Whh + (size_t)n * 512 + colel);
        else if (colel == 512) v = *(const short8*)(Wih + (size_t)n * 8);
        int off = row * W0_STRIDE + uc * 16;
        if (uc < 64) off ^= (row & 7) << 4;
        *(short8*)(lw + off) = v;
    }
}
__device__ __forceinline__ void load_w1(char* lw, const bf16* Wih, const bf16* Whh, int j0, int tid)
{
    for (int u = tid; u < 64 * 128; u += 256) {
        int row = u >> 7, uc = u & 127;
        int n = ((row >> 4) << 9) + j0 + (row & 15);
        int colel = uc << 3;
        short8 v;
        if (colel < 512) v = *(const short8*)(Wih + (size_t)n * 512 + colel);
        else             v = *(const short8*)(Whh + (size_t)n * 512 + (colel - 512));
        *(short8*)(lw + ((row * 2048 + uc * 16) ^ ((row & 7) << 4))) = v;
    }
}

// ---------------- layer-0 step: 4 waves x 2 m-tiles (B-frag reused 2x) ----------------
template<bool DEC>
__device__ __forceinline__ void l0_step(
    const bf16* __restrict__ h0cur, bf16* __restrict__ h0nxt,
    const bf16* __restrict__ xbf, int s,
    const float* __restrict__ partials, const float* __restrict__ fcb,
    float* __restrict__ outp, int t,
    char* lw, bf16* lxs,
    float* cst, const float* bsum,
    int m0, int j0, int jb, int tid)
{
    const int w = tid >> 6;          // m-pair 0..3
    const int l = tid & 63, lr = l & 15, lg = l >> 4;
    const short8 z8 = {0, 0, 0, 0, 0, 0, 0, 0};

    if (DEC) {
        #pragma unroll
        for (int p = 0; p < 4; ++p) {
            int e = p * 256 + tid, mlo = e >> 3, f = e & 7;
            if (t == 0) {
                lxs[mlo * 8 + f] = xbf[((size_t)(m0 + mlo) * 168 + 167) * 8 + f];
            } else {
                float pv[32];
                #pragma unroll
                for (int q = 0; q < 32; ++q)
                    pv[q] = load_f32_wt(partials + q * 2048 + (m0 + mlo) * 8 + f);
                ldrain();
                float sacc = fcb[f];
                #pragma unroll
                for (int q = 0; q < 32; ++q) sacc += pv[q];
                if (jb == 0) outp[(size_t)(m0 + mlo) * 192 + (t - 1) * 8 + f] = sacc;
                ((short*)lxs)[mlo * 8 + f] = f2bf(sacc);
            }
        }
        __syncthreads();   // drains everything; vm count clean below
    }

    // issue all A loads (asm, program-ordered), pairs by k-chunk
    const bf16* ar0 = h0cur + ((size_t)(m0 + (w * 2 + 0) * 16 + lr) << 9) + lg * 8;
    const bf16* ar1 = h0cur + ((size_t)(m0 + (w * 2 + 1) * 16 + lr) << 9) + lg * 8;
    short8 a0[16], a1[16];
    #pragma unroll
    for (int kcg = 0; kcg < 16; ++kcg) {
        a0[kcg] = load_b16x8_wt(ar0 + kcg * 32);
        a1[kcg] = load_b16x8_wt(ar1 + kcg * 32);
    }
    short8 ax0 = z8, ax1 = z8;
    if (!DEC) {
        ax0 = load_b16x8_wt(xbf + ((size_t)(m0 + (w * 2 + 0) * 16 + lr) * 168 + s) * 8);
        ax1 = load_b16x8_wt(xbf + ((size_t)(m0 + (w * 2 + 1) * 16 + lr) * 168 + s) * 8);
    }

    // first half ready: 16 oldest done -> vmcnt = remaining (ENC 34-16=18, DEC 32-16=16)
    asm volatile("s_waitcnt vmcnt(%0)" :: "i"(DEC ? 16 : 18) : "memory");
    __builtin_amdgcn_sched_barrier(0);

    f32x4 acc0[4], acc1[4];
    #pragma unroll
    for (int g = 0; g < 4; ++g) { acc0[g] = (f32x4){0,0,0,0}; acc1[g] = (f32x4){0,0,0,0}; }

    #pragma unroll
    for (int kcg = 0; kcg < 8; ++kcg) {
        #pragma unroll
        for (int g = 0; g < 4; ++g) {
            int wrow = g * 16 + lr;
            short8 bfr = *(const short8*)(lw + ((wrow * W0_STRIDE + kcg * 64 + lg * 16) ^ ((wrow & 7) << 4)));
            acc0[g] = __builtin_amdgcn_mfma_f32_16x16x32_bf16(a0[kcg], bfr, acc0[g], 0, 0, 0);
            acc1[g] = __builtin_amdgcn_mfma_f32_16x16x32_bf16(a1[kcg], bfr, acc1[g], 0, 0, 0);
        }
    }
    ldrain();   // rest of loads done

    if (!DEC) {
        if (lg != 0) { ax0 = z8; ax1 = z8; }
    } else {
        if (lg == 0) {
            ax0 = *(const short8*)(lxs + ((w * 2 + 0) * 16 + lr) * 8);
            ax1 = *(const short8*)(lxs + ((w * 2 + 1) * 16 + lr) * 8);
        }
    }

    #pragma unroll
    for (int kcg = 8; kcg < 16; ++kcg) {
        #pragma unroll
        for (int g = 0; g < 4; ++g) {
            int wrow = g * 16 + lr;
            short8 bfr = *(const short8*)(lw + ((wrow * W0_STRIDE + kcg * 64 + lg * 16) ^ ((wrow & 7) << 4)));
            acc0[g] = __builtin_amdgcn_mfma_f32_16x16x32_bf16(a0[kcg], bfr, acc0[g], 0, 0, 0);
            acc1[g] = __builtin_amdgcn_mfma_f32_16x16x32_bf16(a1[kcg], bfr, acc1[g], 0, 0, 0);
        }
    }
    // x chunk (unswizzled slot at byte 1024)
    #pragma unroll
    for (int g = 0; g < 4; ++g) {
        int wrow = g * 16 + lr;
        short8 bfr = *(const short8*)(lw + wrow * W0_STRIDE + 1024 + lg * 16);
        acc0[g] = __builtin_amdgcn_mfma_f32_16x16x32_bf16(ax0, bfr, acc0[g], 0, 0, 0);
        acc1[g] = __builtin_amdgcn_mfma_f32_16x16x32_bf16(ax1, bfr, acc1[g], 0, 0, 0);
    }

    #pragma unroll
    for (int mi = 0; mi < 2; ++mi) {
        #pragma unroll
        for (int r = 0; r < 4; ++r) {
            float gi = (mi ? acc1[0][r] : acc0[0][r]) + bsum[0];
            float gf = (mi ? acc1[1][r] : acc0[1][r]) + bsum[1];
            float gg = (mi ? acc1[2][r] : acc0[2][r]) + bsum[2];
            float go = (mi ? acc1[3][r] : acc0[3][r]) + bsum[3];
            float cv = sigm(gf) * cst[mi * 4 + r] + sigm(gi) * tanhf(gg);
            float hv = sigm(go) * tanhf(cv);
            cst[mi * 4 + r] = cv;
            store_short_wt(h0nxt + ((size_t)(m0 + (w * 2 + mi) * 16 + lg * 4 + r) << 9) + j0 + lr,
                           f2bf(hv));
        }
    }
}

// ---------------- layer-1 step: 4 waves = 2 k-halves x 2 m-pairs ----------------
template<bool DEC>
__device__ __forceinline__ void l1_step(
    const bf16* __restrict__ h0src, const bf16* __restrict__ h1prev, bf16* __restrict__ h1nxt,
    float* __restrict__ partials, const float* __restrict__ wf,
    char* lw, float* lgl,
    float* cst, const float* bsum,
    int m0, int j0, int jb, int tid)
{
    const int w = tid >> 6, kh = w >> 1, mp = w & 1;
    const int l = tid & 63, lr = l & 15, lg = l >> 4;
    const bf16* A = (kh == 0) ? h0src : h1prev;
    const int colbase = (kh == 0) ? 0 : 1024;

    const bf16* ar0 = A + ((size_t)(m0 + (mp * 2 + 0) * 16 + lr) << 9) + lg * 8;
    const bf16* ar1 = A + ((size_t)(m0 + (mp * 2 + 1) * 16 + lr) << 9) + lg * 8;
    short8 a0[16], a1[16];
    #pragma unroll
    for (int kc = 0; kc < 16; ++kc) {
        a0[kc] = load_b16x8_wt(ar0 + kc * 32);
        a1[kc] = load_b16x8_wt(ar1 + kc * 32);
    }
    asm volatile("s_waitcnt vmcnt(16)" ::: "memory");   // pairs 0..7 done
    __builtin_amdgcn_sched_barrier(0);

    f32x4 acc0[4], acc1[4];
    #pragma unroll
    for (int g = 0; g < 4; ++g) { acc0[g] = (f32x4){0,0,0,0}; acc1[g] = (f32x4){0,0,0,0}; }

    #pragma unroll
    for (int kc = 0; kc < 8; ++kc) {
        #pragma unroll
        for (int g = 0; g < 4; ++g) {
            int wrow = g * 16 + lr;
            short8 bfr = *(const short8*)(lw + ((wrow * 2048 + colbase + kc * 64 + lg * 16) ^ ((wrow & 7) << 4)));
            acc0[g] = __builtin_amdgcn_mfma_f32_16x16x32_bf16(a0[kc], bfr, acc0[g], 0, 0, 0);
            acc1[g] = __builtin_amdgcn_mfma_f32_16x16x32_bf16(a1[kc], bfr, acc1[g], 0, 0, 0);
        }
    }
    ldrain();
    #pragma unroll
    for (int kc = 8; kc < 16; ++kc) {
        #pragma unroll
        for (int g = 0; g < 4; ++g) {
            int wrow = g * 16 + lr;
            short8 bfr = *(const short8*)(lw + ((wrow * 2048 + colbase + kc * 64 + lg * 16) ^ ((wrow & 7) << 4)));
            acc0[g] = __builtin_amdgcn_mfma_f32_16x16x32_bf16(a0[kc], bfr, acc0[g], 0, 0, 0);
            acc1[g] = __builtin_amdgcn_mfma_f32_16x16x32_bf16(a1[kc], bfr, acc1[g], 0, 0, 0);
        }
    }

    if (kh == 1) {
        #pragma unroll
        for (int mi = 0; mi < 2; ++mi)
            #pragma unroll
            for (int g = 0; g < 4; ++g)
                #pragma unroll
                for (int r = 0; r < 4; ++r)
                    lgl[(g * 64 + (mp * 2 + mi) * 16 + lg * 4 + r) * 16 + lr] =
                        (mi ? acc1[g][r] : acc0[g][r]);
    }
    __syncthreads();
    if (kh == 0) {
        #pragma unroll
        for (int mi = 0; mi < 2; ++mi) {
            #pragma unroll
            for (int r = 0; r < 4; ++r) {
                int mrow = (mp * 2 + mi) * 16 + lg * 4 + r;
                float gi = (mi ? acc1[0][r] : acc0[0][r]) + lgl[(0 * 64 + mrow) * 16 + lr] + bsum[0];
                float gf = (mi ? acc1[1][r] : acc0[1][r]) + lgl[(1 * 64 + mrow) * 16 + lr] + bsum[1];
                float gg = (mi ? acc1[2][r] : acc0[2][r]) + lgl[(2 * 64 + mrow) * 16 + lr] + bsum[2];
                float go = (mi ? acc1[3][r] : acc0[3][r]) + lgl[(3 * 64 + mrow) * 16 + lr] + bsum[3];
                float cv = sigm(gf) * cst[mi * 4 + r] + sigm(gi) * tanhf(gg);
                float hv = sigm(go) * tanhf(cv);
                cst[mi * 4 + r] = cv;
                store_short_wt(h1nxt + ((size_t)(m0 + mrow) << 9) + j0 + lr, f2bf(hv));
                if (DEC) {
                    #pragma unroll
                    for (int f = 0; f < 8; ++f) {
                        float v = hv * wf[f];
                        v += __shfl_xor(v, 1); v += __shfl_xor(v, 2);
                        v += __shfl_xor(v, 4); v += __shfl_xor(v, 8);
                        if (lr == f)
                            store_dword_wt(partials + jb * 2048 + (m0 + mrow) * 8 + f, v);
                    }
                }
            }
        }
    }
}

// ---------------- persistent kernel ----------------
__global__ __launch_bounds__(256, 1) void net_kernel(KArgs a)
{
    extern __shared__ char smem[];
    const int tid = threadIdx.x;
    const int bid = blockIdx.x;
    const int role = (bid < 64) ? 0 : 1;
    const int sub = role == 0 ? bid : bid - 64;
    const int jb = sub & 31;
    const int grp = sub >> 5;
    const int m0 = (role == 0) ? grp * 128 : grp * 64;
    const int j0 = jb * 16;
    const int mh = (role == 0) ? grp : (grp >> 1);

    unsigned* cnt = a.cnt;
    unsigned* mycnt = cnt + ((role == 0) ? (grp * 32 + jb) : (64 + grp * 32 + jb)) * 32;
    const unsigned* l0grp = cnt + (mh * 32) * 32;
    const unsigned* l1cat = cnt + (64 + 2 * mh * 32) * 32;
    const unsigned* l1grp = cnt + (64 + grp * 32) * 32;

    char* lw  = smem;
    float* lgl = (float*)(smem + 131072);
    bf16* lxs  = (bf16*)(smem + 64 * W0_STRIDE);

    bf16* B0[3] = { a.h0base, a.h0base + 131072, a.h0base + 262144 };
    bf16* B1[3] = { a.h1base, a.h1base + 131072, a.h1base + 262144 };

    if (role == 0) load_w0(lw, a.eWhh0, a.eWih0, j0, tid);
    else           load_w1(lw, a.eWih1, a.eWhh1, j0, tid);

    float bsum[4];
    {
        const float* bi = role == 0 ? a.ebih0 : a.ebih1;
        const float* bh = role == 0 ? a.ebhh0 : a.ebhh1;
        #pragma unroll
        for (int g2 = 0; g2 < 4; ++g2) {
            int n = (g2 << 9) + j0 + (tid & 15);
            bsum[g2] = bi[n] + bh[n];
        }
    }
    float cst[8] = {0.f, 0.f, 0.f, 0.f, 0.f, 0.f, 0.f, 0.f};
    float wf[8]  = {0.f, 0.f, 0.f, 0.f, 0.f, 0.f, 0.f, 0.f};
    __syncthreads();

    if (role == 0) {
        for (int p = 0; p < 192; ++p) {
            const bool dec = p >= 168;
            if (p == 168) {
                load_w0(lw, a.dWhh0, a.dWih0, j0, tid);
                #pragma unroll
                for (int g2 = 0; g2 < 4; ++g2) {
                    int n = (g2 << 9) + j0 + (tid & 15);
                    bsum[g2] = a.dbih0[n] + a.dbhh0[n];
                }
                __syncthreads();
            }
            unsigned t1 = (unsigned)p;
            unsigned t2 = (p >= 169) ? (unsigned)p : (p >= 2 ? (unsigned)(p - 2) : 0u);
            pollw(l0grp, t1, 32, l1cat, t2, 64, tid);

            if (!dec)
                l0_step<false>(B0[(p + 2) % 3], B0[p % 3], a.xbf, p,
                               nullptr, nullptr, nullptr, 0,
                               lw, lxs, cst, bsum, m0, j0, jb, tid);
            else
                l0_step<true>(B0[(p + 2) % 3], B0[p % 3], a.xbf, 0,
                              a.partials, a.fcb, a.outp, p - 168,
                              lw, lxs, cst, bsum, m0, j0, jb, tid);
            publish(mycnt, (unsigned)(p + 1), tid);
        }
        if (jb == 0) {
            pollw(l1cat, 192u, 64, nullptr, 0u, 0, tid);
            #pragma unroll
            for (int p2 = 0; p2 < 4; ++p2) {
                int e = p2 * 256 + tid, mlo = e >> 3, f = e & 7;
                float pv[32];
                #pragma unroll
                for (int q = 0; q < 32; ++q)
                    pv[q] = load_f32_wt(a.partials + q * 2048 + (m0 + mlo) * 8 + f);
                ldrain();
                float sacc = a.fcb[f];
                #pragma unroll
                for (int q = 0; q < 32; ++q) sacc += pv[q];
                a.outp[(size_t)(m0 + mlo) * 192 + 23 * 8 + f] = sacc;
            }
        }
    } else {
        for (int q = 0; q < 192; ++q) {
            const bool dec = q >= 168;
            if (q == 168) {
                load_w1(lw, a.dWih1, a.dWhh1, j0, tid);
                #pragma unroll
                for (int g2 = 0; g2 < 4; ++g2) {
                    int n = (g2 << 9) + j0 + (tid & 15);
                    bsum[g2] = a.dbih1[n] + a.dbhh1[n];
                }
                #pragma unroll
                for (int f = 0; f < 8; ++f) wf[f] = a.fcW[f * 512 + j0 + (tid & 15)];
                __syncthreads();
            }
            pollw(l0grp, (unsigned)(q + 1), 32, l1grp, (unsigned)q, 32, tid);

            if (!dec)
                l1_step<false>(B0[q % 3], B1[(q + 2) % 3], B1[q % 3],
                               nullptr, nullptr, lw, lgl, cst, bsum, m0, j0, jb, tid);
            else
                l1_step<true>(B0[q % 3], B1[(q + 2) % 3], B1[q % 3],
                              a.partials, wf, lw, lgl, cst, bsum, m0, j0, jb, tid);
            publish(mycnt, (unsigned)(q + 1), tid);
        }
    }
}

extern "C" void kernel_launch(void* const* d_in, const int* in_sizes, int n_in,
                              void* d_out, int out_size, void* d_ws, size_t ws_size,
                              hipStream_t stream)
{
    (void)in_sizes; (void)n_in; (void)out_size; (void)ws_size;
    const float* src   = (const float*)d_in[0];
    const float* eWih0 = (const float*)d_in[1];
    const float* eWhh0 = (const float*)d_in[2];
    const float* ebih0 = (const float*)d_in[3];
    const float* ebhh0 = (const float*)d_in[4];
    const float* eWih1 = (const float*)d_in[5];
    const float* eWhh1 = (const float*)d_in[6];
    const float* ebih1 = (const float*)d_in[7];
    const float* ebhh1 = (const float*)d_in[8];
    const float* dWih0 = (const float*)d_in[9];
    const float* dWhh0 = (const float*)d_in[10];
    const float* dbih0 = (const float*)d_in[11];
    const float* dbhh0 = (const float*)d_in[12];
    const float* dWih1 = (const float*)d_in[13];
    const float* dWhh1 = (const float*)d_in[14];
    const float* dbih1 = (const float*)d_in[15];
    const float* dbhh1 = (const float*)d_in[16];
    const float* fcW   = (const float*)d_in[17];
    const float* fcb   = (const float*)d_in[18];

    char* ws = (char*)d_ws;
    const int NH = 2048 * 512;

    CvtArgs ca;
    ca.e[0] = { eWhh0, (bf16*)(ws + WS_W + 0x000000), NH };
    ca.e[1] = { eWih1, (bf16*)(ws + WS_W + 0x200000), NH };
    ca.e[2] = { eWhh1, (bf16*)(ws + WS_W + 0x400000), NH };
    ca.e[3] = { dWhh0, (bf16*)(ws + WS_W + 0x600000), NH };
    ca.e[4] = { dWih1, (bf16*)(ws + WS_W + 0x800000), NH };
    ca.e[5] = { dWhh1, (bf16*)(ws + WS_W + 0xA00000), NH };
    ca.e[6] = { eWih0, (bf16*)(ws + WS_EWIH0), 2048 * 8 };
    ca.e[7] = { dWih0, (bf16*)(ws + WS_DWIH0), 2048 * 8 };
    ca.e[8] = { src,   (bf16*)(ws + WS_XBF),   256 * 168 * 8 };

    KArgs ka;
    ka.xbf   = (const bf16*)(ws + WS_XBF);
    ka.eWhh0 = (const bf16*)(ws + WS_W + 0x000000);
    ka.eWih1 = (const bf16*)(ws + WS_W + 0x200000);
    ka.eWhh1 = (const bf16*)(ws + WS_W + 0x400000);
    ka.dWhh0 = (const bf16*)(ws + WS_W + 0x600000);
    ka.dWih1 = (const bf16*)(ws + WS_W + 0x800000);
    ka.dWhh1 = (const bf16*)(ws + WS_W + 0xA00000);
    ka.eWih0 = (const bf16*)(ws + WS_EWIH0);
    ka.dWih0 = (const bf16*)(ws + WS_DWIH0);
    ka.ebih0 = ebih0; ka.ebhh0 = ebhh0; ka.ebih1 = ebih1; ka.ebhh1 = ebhh1;
    ka.dbih0 = dbih0; ka.dbhh0 = dbhh0; ka.dbih1 = dbih1; ka.dbhh1 = dbhh1;
    ka.fcW = fcW; ka.fcb = fcb;
    ka.h0base = (bf16*)(ws + WS_H0);
    ka.h1base = (bf16*)(ws + WS_H1);
    ka.partials = (float*)(ws + WS_PART);
    ka.cnt      = (unsigned*)(ws + WS_CNT);
    ka.outp     = (float*)d_out;

    hipFuncSetAttribute((const void*)net_kernel,
                        hipFuncAttributeMaxDynamicSharedMemorySize, SMEM_BYTES);

    convert_kernel<<<dim3(128, 9), dim3(256), 0, stream>>>(ca);
    init_kernel<<<dim3(512), dim3(256), 0, stream>>>((unsigned int*)ws);
    net_kernel<<<dim3(NBLK), dim3(256), SMEM_BYTES, stream>>>(ka);
}